// Round 4
// baseline (252.553 us; speedup 1.0000x reference)
//
#include <hip/hip_runtime.h>
#include <hip/hip_bf16.h>
#include <math.h>

typedef __bf16 bf16;
typedef __bf16 bf16x8 __attribute__((ext_vector_type(8)));
typedef __bf16 bf16x4 __attribute__((ext_vector_type(4)));
typedef float  f32x4  __attribute__((ext_vector_type(4)));

#define MFMA(a, b, c) __builtin_amdgcn_mfma_f32_16x16x32_bf16((a), (b), (c), 0, 0, 0)
#define LOG2E 1.4426950408889634f

// ---------------------------------------------------------------------------
// Kernel 0: precast w_qkv^T -> wqT (bf16 [576][192]) and w_proj^T -> wpT
// (bf16 [192][192]).
// ---------------------------------------------------------------------------
__global__ void precast_kernel(const float* __restrict__ w_qkv,
                               const float* __restrict__ w_proj,
                               bf16* __restrict__ wqT, bf16* __restrict__ wpT) {
  int idx = blockIdx.x * 256 + threadIdx.x;
  if (idx < 576 * 192) {
    int c = idx / 192, k = idx % 192;
    wqT[idx] = (bf16)w_qkv[k * 576 + c];
  } else {
    int i2 = idx - 576 * 192;
    if (i2 < 192 * 192) {
      int c = i2 / 192, k = i2 % 192;
      wpT[i2] = (bf16)w_proj[k * 192 + c];
    }
  }
}

// ---------------------------------------------------------------------------
// Kernel A: relative-position-bias MLP (961 rows, 2->12->12->12->6).
// Output pos_out[h][i] (head-major).
// ---------------------------------------------------------------------------
__global__ void pos_mlp_kernel(
    const float* __restrict__ pw0, const float* __restrict__ pb0,
    const float* __restrict__ g1,  const float* __restrict__ be1,
    const float* __restrict__ w1,  const float* __restrict__ b1,
    const float* __restrict__ g2,  const float* __restrict__ be2,
    const float* __restrict__ w2,  const float* __restrict__ b2,
    const float* __restrict__ g3,  const float* __restrict__ be3,
    const float* __restrict__ w3,  const float* __restrict__ b3,
    float* __restrict__ pos_out) {
  int i = blockIdx.x * blockDim.x + threadIdx.x;
  if (i >= 961) return;
  float bh = (float)(i / 31) - 15.0f;
  float bw = (float)(i % 31) - 15.0f;
  float xv[12];
#pragma unroll
  for (int j = 0; j < 12; j++) xv[j] = bh * pw0[j] + bw * pw0[12 + j] + pb0[j];
  const float* G[3]  = {g1, g2, g3};
  const float* BE[3] = {be1, be2, be3};
  const float* W[3]  = {w1, w2, w3};
  const float* BB[3] = {b1, b2, b3};
#pragma unroll
  for (int s = 0; s < 3; s++) {
    float m = 0.f;
#pragma unroll
    for (int j = 0; j < 12; j++) m += xv[j];
    m *= (1.0f / 12.0f);
    float v = 0.f;
#pragma unroll
    for (int j = 0; j < 12; j++) { float d = xv[j] - m; v += d * d; }
    v *= (1.0f / 12.0f);
    float inv = 1.0f / sqrtf(v + 1e-5f);
    float y[12];
#pragma unroll
    for (int j = 0; j < 12; j++) {
      float t = (xv[j] - m) * inv * G[s][j] + BE[s][j];
      y[j] = t > 0.f ? t : 0.f;
    }
    int oc = (s == 2) ? 6 : 12;
    float on[12];
    for (int c = 0; c < oc; c++) {
      float acc = BB[s][c];
#pragma unroll
      for (int j = 0; j < 12; j++) acc += y[j] * W[s][j * oc + c];
      on[c] = acc;
    }
    for (int c = 0; c < 12; c++) xv[c] = (c < oc) ? on[c] : 0.f;
  }
  for (int hh = 0; hh < 6; hh++) pos_out[hh * 961 + i] = xv[hh];
}

// ---------------------------------------------------------------------------
// Kernel B: QKV GEMM, zero LDS.  grid 1024, 4 waves x 16 rows (BM=64).
// Q is pre-scaled by scale*log2e (folded softmax scaling).
// Q,K: swapped MFMA -> bf16x4 stores to [b][h][n][d]; V -> vT[b][h][d][n].
// ---------------------------------------------------------------------------
__global__ __launch_bounds__(256) void qkv_gemm_kernel(
    const float* __restrict__ x, const bf16* __restrict__ wqT,
    const float* __restrict__ b_qkv, bf16* __restrict__ qw,
    bf16* __restrict__ kw, bf16* __restrict__ vwT) {
  const int tid = threadIdx.x;
  const int lane = tid & 63, w = tid >> 6;
  const int cI = lane & 15, gI = lane >> 4;
  const int row0 = blockIdx.x * 64 + w * 16;
  const float QSCALE = 0.17677669529663687f * LOG2E;

  bf16x8 afr[6];
#pragma unroll
  for (int kk = 0; kk < 6; kk++) {
    const float* p = x + (size_t)(row0 + cI) * 192 + kk * 32 + gI * 8;
    float4 f0 = *(const float4*)p;
    float4 f1 = *(const float4*)(p + 4);
    bf16x8 a;
    a[0] = (bf16)f0.x; a[1] = (bf16)f0.y; a[2] = (bf16)f0.z; a[3] = (bf16)f0.w;
    a[4] = (bf16)f1.x; a[5] = (bf16)f1.y; a[6] = (bf16)f1.z; a[7] = (bf16)f1.w;
    afr[kk] = a;
  }
  const int b = row0 >> 8;

#pragma unroll
  for (int mat = 0; mat < 3; mat++) {
#pragma unroll
    for (int ct = 0; ct < 12; ct++) {
      bf16x8 wfr[6];
#pragma unroll
      for (int kk = 0; kk < 6; kk++)
        wfr[kk] = *(const bf16x8*)(wqT + (size_t)(mat * 192 + ct * 16 + cI) * 192 +
                                   kk * 32 + gI * 8);
      if (mat < 2) {
        // swapped: col c at row-slot (gI*4+r), row n at col-slot cI
        f32x4 bv4 = *(const f32x4*)(b_qkv + mat * 192 + ct * 16 + gI * 4);
        bf16* dst = (mat == 0) ? qw : kw;
        f32x4 acc = {0.f, 0.f, 0.f, 0.f};
#pragma unroll
        for (int kk = 0; kk < 6; kk++) acc = MFMA(wfr[kk], afr[kk], acc);
        int n = (row0 + cI) & 255;
        int c0 = ct * 16 + gI * 4;
        int h = c0 >> 5, d0 = c0 & 31;
        bf16x4 o4;
        if (mat == 0) {
#pragma unroll
          for (int r = 0; r < 4; r++) o4[r] = (bf16)((acc[r] + bv4[r]) * QSCALE);
        } else {
#pragma unroll
          for (int r = 0; r < 4; r++) o4[r] = (bf16)(acc[r] + bv4[r]);
        }
        *(bf16x4*)(dst + ((size_t)(b * 6 + h) * 256 + n) * 32 + d0) = o4;
      } else {
        float bv = b_qkv[384 + ct * 16 + cI];
        int c = ct * 16 + cI, h = c >> 5, d = c & 31;
        f32x4 acc = {0.f, 0.f, 0.f, 0.f};
#pragma unroll
        for (int kk = 0; kk < 6; kk++) acc = MFMA(afr[kk], wfr[kk], acc);
        int n0 = (row0 & 255) + gI * 4;
        bf16x4 o4;
#pragma unroll
        for (int r = 0; r < 4; r++) o4[r] = (bf16)(acc[r] + bv);
        *(bf16x4*)(vwT + ((size_t)(b * 6 + h) * 32 + d) * 256 + n0) = o4;
      }
    }
  }
}

// ---------------------------------------------------------------------------
// Kernel C: flash attention, swapped-QK^T orientation.  grid 3072 (b,h,half),
// 4 waves x 32 Q rows.  Scores S' = (Q*s*log2e)K^T + (pos+mask)*log2e; P=2^..
// LDS: posh[961]f32 @0 (pad 3904) | pw 4 x [32][72] bf16 @3904.
// ---------------------------------------------------------------------------
#define SM_PW2   3904
#define SMEM_A   22336

__global__ __launch_bounds__(256, 4) void attn_kernel(
    const bf16* __restrict__ qw, const bf16* __restrict__ kw,
    const bf16* __restrict__ vwT, const float* __restrict__ mask,
    const float* __restrict__ posg, bf16* __restrict__ ctx) {
  extern __shared__ char smem[];
  float* posh = (float*)smem;

  const int tid = threadIdx.x;
  const int bid = blockIdx.x;
  const int s_ = bid & 63, j_ = bid >> 6;          // mask slice; XCD = s%8
  const int g_ = j_ & 3, t2 = j_ >> 2;
  const int h = t2 % 6, half = t2 / 6;
  const int b = g_ * 64 + s_;

  const bf16* qb = qw  + (size_t)(b * 6 + h) * 8192;
  const bf16* kb = kw  + (size_t)(b * 6 + h) * 8192;
  const bf16* vb = vwT + (size_t)(b * 6 + h) * 8192;

  for (int i2 = tid; i2 < 961; i2 += 256) posh[i2] = posg[h * 961 + i2];
  __syncthreads();

  const int lane = tid & 63, w = tid >> 6;
  const int cI = lane & 15, gI = lane >> 4;
  const int qrow0 = half * 128 + w * 32;
  bf16* pw = (bf16*)(smem + SM_PW2 + w * 4608);    // per-wave [32][72]

  bf16x8 qfr[2];
#pragma unroll
  for (int rt = 0; rt < 2; rt++)
    qfr[rt] = *(const bf16x8*)(qb + (qrow0 + rt * 16 + cI) * 32 + gI * 8);

  const float* maskb = mask + (size_t)s_ * (256 * 256);

  f32x4 o[2][2];
  float mr[2], lr[2];
#pragma unroll
  for (int rt = 0; rt < 2; rt++) {
    o[rt][0] = (f32x4){0.f, 0.f, 0.f, 0.f};
    o[rt][1] = (f32x4){0.f, 0.f, 0.f, 0.f};
    mr[rt] = -3.0e38f; lr[rt] = 0.f;
  }

  for (int kt = 0; kt < 4; kt++) {
    bf16x8 kfr[4];
#pragma unroll
    for (int ct = 0; ct < 4; ct++)
      kfr[ct] = *(const bf16x8*)(kb + (kt * 64 + ct * 16 + cI) * 32 + gI * 8);
    f32x4 sa[2][4];
#pragma unroll
    for (int rt = 0; rt < 2; rt++) {
#pragma unroll
      for (int ct = 0; ct < 4; ct++) {
        f32x4 z = {0.f, 0.f, 0.f, 0.f};
        sa[rt][ct] = MFMA(kfr[ct], qfr[rt], z);   // swapped: m@row-slot, n@cI
      }
    }
    // bias: pos tile-constant base, mask f32x4 (4-lane groups = full lines)
#pragma unroll
    for (int rt = 0; rt < 2; rt++) {
      int rnb = (qrow0 >> 4) + rt;
      const float* mrow = maskb + (size_t)(qrow0 + rt * 16 + cI) * 256 + kt * 64;
#pragma unroll
      for (int ct = 0; ct < 4; ct++) {
        int base = (rnb - (kt * 4 + ct) + 15) * 31 + cI + 15 - gI * 4;
        f32x4 mv = *(const f32x4*)(mrow + ct * 16 + gI * 4);
#pragma unroll
        for (int r = 0; r < 4; r++)
          sa[rt][ct][r] = fmaf(posh[base - r] + mv[r], LOG2E, sa[rt][ct][r]);
      }
    }
    // softmax: in-lane 16-reduce + 2 shuffles (row = q at lane cI)
#pragma unroll
    for (int rt = 0; rt < 2; rt++) {
      float t = sa[rt][0][0];
#pragma unroll
      for (int ct = 0; ct < 4; ct++)
#pragma unroll
        for (int r = 0; r < 4; r++) t = fmaxf(t, sa[rt][ct][r]);
      t = fmaxf(t, __shfl_xor(t, 16));
      t = fmaxf(t, __shfl_xor(t, 32));
      float mn = fmaxf(mr[rt], t);
      float fsc = exp2f(mr[rt] - mn);
      mr[rt] = mn;
      float sum = 0.f;
#pragma unroll
      for (int ct = 0; ct < 4; ct++)
#pragma unroll
        for (int r = 0; r < 4; r++) {
          float pp = exp2f(sa[rt][ct][r] - mn);
          sa[rt][ct][r] = pp;
          sum += pp;
        }
      sum += __shfl_xor(sum, 16);
      sum += __shfl_xor(sum, 32);
      lr[rt] = lr[rt] * fsc + sum;
      float fr0 = __shfl(fsc, gI * 4 + 0);
      float fr1 = __shfl(fsc, gI * 4 + 1);
      float fr2 = __shfl(fsc, gI * 4 + 2);
      float fr3 = __shfl(fsc, gI * 4 + 3);
      o[rt][0][0] *= fr0; o[rt][1][0] *= fr0;
      o[rt][0][1] *= fr1; o[rt][1][1] *= fr1;
      o[rt][0][2] *= fr2; o[rt][1][2] *= fr2;
      o[rt][0][3] *= fr3; o[rt][1][3] *= fr3;
#pragma unroll
      for (int ct = 0; ct < 4; ct++) {
        bf16x4 p4;
#pragma unroll
        for (int r = 0; r < 4; r++) p4[r] = (bf16)sa[rt][ct][r];
        *(bf16x4*)(pw + (rt * 16 + cI) * 72 + ct * 16 + gI * 4) = p4;
      }
    }
    // this wave's P writes must land before re-reading as A-frags
    asm volatile("s_waitcnt lgkmcnt(0)" ::: "memory");
    __builtin_amdgcn_sched_barrier(0);
#pragma unroll
    for (int kc = 0; kc < 2; kc++) {
      bf16x8 pfr[2], vfr[2];
#pragma unroll
      for (int rt = 0; rt < 2; rt++)
        pfr[rt] = *(const bf16x8*)(pw + (rt * 16 + cI) * 72 + kc * 32 + gI * 8);
#pragma unroll
      for (int c2 = 0; c2 < 2; c2++)
        vfr[c2] = *(const bf16x8*)(vb + (c2 * 16 + cI) * 256 + kt * 64 + kc * 32 + gI * 8);
#pragma unroll
      for (int rt = 0; rt < 2; rt++) {
#pragma unroll
        for (int c2 = 0; c2 < 2; c2++)
          o[rt][c2] = MFMA(pfr[rt], vfr[c2], o[rt][c2]);
      }
    }
  }
  // ---- epilogue: lr lives at lane cI -> shuffle to row-slot, normalize ----
#pragma unroll
  for (int rt = 0; rt < 2; rt++) {
    float l0 = __shfl(lr[rt], gI * 4 + 0);
    float l1 = __shfl(lr[rt], gI * 4 + 1);
    float l2 = __shfl(lr[rt], gI * 4 + 2);
    float l3 = __shfl(lr[rt], gI * 4 + 3);
    f32x4 linv = {1.f / l0, 1.f / l1, 1.f / l2, 1.f / l3};
#pragma unroll
    for (int c2 = 0; c2 < 2; c2++) {
#pragma unroll
      for (int r = 0; r < 4; r++) {
        int n = qrow0 + rt * 16 + gI * 4 + r;
        ctx[((size_t)(b << 8) + n) * 192 + h * 32 + c2 * 16 + cI] =
            (bf16)(o[rt][c2][r] * linv[r]);
      }
    }
  }
}

// ---------------------------------------------------------------------------
// Kernel D: out = ctx @ w_proj + b_proj, zero LDS (wpT precast), swapped
// orientation -> float4 stores.  grid 1024, 4 waves x 16 rows.
// ---------------------------------------------------------------------------
__global__ __launch_bounds__(256) void proj_kernel(
    const bf16* __restrict__ ctx, const bf16* __restrict__ wpT,
    const float* __restrict__ b_proj, float* __restrict__ out) {
  const int tid = threadIdx.x;
  const int lane = tid & 63, w = tid >> 6;
  const int cI = lane & 15, gI = lane >> 4;
  const int row0 = blockIdx.x * 64 + w * 16;
  bf16x8 afr[6];
#pragma unroll
  for (int kk = 0; kk < 6; kk++)
    afr[kk] = *(const bf16x8*)(ctx + (size_t)(row0 + cI) * 192 + kk * 32 + gI * 8);
#pragma unroll
  for (int ct = 0; ct < 12; ct++) {
    bf16x8 wfr[6];
#pragma unroll
    for (int kk = 0; kk < 6; kk++)
      wfr[kk] = *(const bf16x8*)(wpT + (size_t)(ct * 16 + cI) * 192 + kk * 32 + gI * 8);
    f32x4 bv4 = *(const f32x4*)(b_proj + ct * 16 + gI * 4);
    f32x4 acc = {0.f, 0.f, 0.f, 0.f};
#pragma unroll
    for (int kk = 0; kk < 6; kk++) acc = MFMA(wfr[kk], afr[kk], acc);
    f32x4 res;
#pragma unroll
    for (int r = 0; r < 4; r++) res[r] = acc[r] + bv4[r];
    *(f32x4*)(out + (size_t)(row0 + cI) * 192 + ct * 16 + gI * 4) = res;
  }
}

// ---------------------------------------------------------------------------
extern "C" void kernel_launch(void* const* d_in, const int* in_sizes, int n_in,
                              void* d_out, int out_size, void* d_ws, size_t ws_size,
                              hipStream_t stream) {
  (void)in_sizes; (void)n_in; (void)out_size; (void)ws_size;
  const float* x      = (const float*)d_in[0];
  const float* mask   = (const float*)d_in[1];
  const float* w_qkv  = (const float*)d_in[2];
  const float* b_qkv  = (const float*)d_in[3];
  const float* w_proj = (const float*)d_in[4];
  const float* b_proj = (const float*)d_in[5];
  const float* pw0    = (const float*)d_in[6];
  const float* pb0    = (const float*)d_in[7];
  const float* g1     = (const float*)d_in[8];
  const float* be1    = (const float*)d_in[9];
  const float* w1     = (const float*)d_in[10];
  const float* b1     = (const float*)d_in[11];
  const float* g2     = (const float*)d_in[12];
  const float* be2    = (const float*)d_in[13];
  const float* w2     = (const float*)d_in[14];
  const float* b2     = (const float*)d_in[15];
  const float* g3     = (const float*)d_in[16];
  const float* be3    = (const float*)d_in[17];
  const float* w3     = (const float*)d_in[18];
  const float* b3     = (const float*)d_in[19];

  // ws layout (peak ~96.3 MB):
  //   posw @ 0         (24576)
  //   wqT  @ 24576     (221184)   bf16 [576][192]
  //   wpT  @ 245760    (73728)    bf16 [192][192]
  //   qw   @ 319488    (25165824) bf16 [b][h][n][32]   (pre-scaled by s*log2e)
  //   kw   @ 25485312  (25165824)
  //   vwT  @ 50651136  (25165824) bf16 [b][h][32][n]
  //   ctx  @ 75816960  (25165824)
  char* ws = (char*)d_ws;
  float* posw = (float*)ws;
  bf16*  wqT  = (bf16*)(ws + 24576);
  bf16*  wpT  = (bf16*)(ws + 245760);
  bf16*  qw   = (bf16*)(ws + 319488);
  bf16*  kw   = (bf16*)(ws + 25485312);
  bf16*  vwT  = (bf16*)(ws + 50651136);
  bf16*  ctx  = (bf16*)(ws + 75816960);
  float* outp = (float*)d_out;

  precast_kernel<<<dim3(576), dim3(256), 0, stream>>>(w_qkv, w_proj, wqT, wpT);
  pos_mlp_kernel<<<dim3(4), dim3(256), 0, stream>>>(
      pw0, pb0, g1, be1, w1, b1, g2, be2, w2, b2, g3, be3, w3, b3, posw);
  qkv_gemm_kernel<<<dim3(1024), dim3(256), 0, stream>>>(
      x, wqT, b_qkv, qw, kw, vwT);
  attn_kernel<<<dim3(3072), dim3(256), SMEM_A, stream>>>(
      qw, kw, vwT, mask, posw, ctx);
  proj_kernel<<<dim3(1024), dim3(256), 0, stream>>>(
      ctx, wpT, b_proj, outp);
}

// Round 5
// 145.654 us; speedup vs baseline: 1.7339x; 1.7339x over previous
//
#include <hip/hip_runtime.h>
#include <hip/hip_bf16.h>
#include <math.h>

typedef __bf16 bf16;
typedef __bf16 bf16x8 __attribute__((ext_vector_type(8)));
typedef __bf16 bf16x4 __attribute__((ext_vector_type(4)));
typedef float  f32x4  __attribute__((ext_vector_type(4)));

#define MFMA(a, b, c) __builtin_amdgcn_mfma_f32_16x16x32_bf16((a), (b), (c), 0, 0, 0)
#define LOG2E 1.4426950408889634f

// ---------------------------------------------------------------------------
// Kernel 0: precast w_qkv^T -> wqT (bf16 [576][192]) and w_proj^T -> wpT
// (bf16 [192][192]).
// ---------------------------------------------------------------------------
__global__ void precast_kernel(const float* __restrict__ w_qkv,
                               const float* __restrict__ w_proj,
                               bf16* __restrict__ wqT, bf16* __restrict__ wpT) {
  int idx = blockIdx.x * 256 + threadIdx.x;
  if (idx < 576 * 192) {
    int c = idx / 192, k = idx % 192;
    wqT[idx] = (bf16)w_qkv[k * 576 + c];
  } else {
    int i2 = idx - 576 * 192;
    if (i2 < 192 * 192) {
      int c = i2 / 192, k = i2 % 192;
      wpT[i2] = (bf16)w_proj[k * 192 + c];
    }
  }
}

// ---------------------------------------------------------------------------
// Kernel A: relative-position-bias MLP (961 rows, 2->12->12->12->6).
// Output pos_out[h][i] (head-major).
// ---------------------------------------------------------------------------
__global__ void pos_mlp_kernel(
    const float* __restrict__ pw0, const float* __restrict__ pb0,
    const float* __restrict__ g1,  const float* __restrict__ be1,
    const float* __restrict__ w1,  const float* __restrict__ b1,
    const float* __restrict__ g2,  const float* __restrict__ be2,
    const float* __restrict__ w2,  const float* __restrict__ b2,
    const float* __restrict__ g3,  const float* __restrict__ be3,
    const float* __restrict__ w3,  const float* __restrict__ b3,
    float* __restrict__ pos_out) {
  int i = blockIdx.x * blockDim.x + threadIdx.x;
  if (i >= 961) return;
  float bh = (float)(i / 31) - 15.0f;
  float bw = (float)(i % 31) - 15.0f;
  float xv[12];
#pragma unroll
  for (int j = 0; j < 12; j++) xv[j] = bh * pw0[j] + bw * pw0[12 + j] + pb0[j];
  const float* G[3]  = {g1, g2, g3};
  const float* BE[3] = {be1, be2, be3};
  const float* W[3]  = {w1, w2, w3};
  const float* BB[3] = {b1, b2, b3};
#pragma unroll
  for (int s = 0; s < 3; s++) {
    float m = 0.f;
#pragma unroll
    for (int j = 0; j < 12; j++) m += xv[j];
    m *= (1.0f / 12.0f);
    float v = 0.f;
#pragma unroll
    for (int j = 0; j < 12; j++) { float d = xv[j] - m; v += d * d; }
    v *= (1.0f / 12.0f);
    float inv = 1.0f / sqrtf(v + 1e-5f);
    float y[12];
#pragma unroll
    for (int j = 0; j < 12; j++) {
      float t = (xv[j] - m) * inv * G[s][j] + BE[s][j];
      y[j] = t > 0.f ? t : 0.f;
    }
    int oc = (s == 2) ? 6 : 12;
    float on[12];
    for (int c = 0; c < oc; c++) {
      float acc = BB[s][c];
#pragma unroll
      for (int j = 0; j < 12; j++) acc += y[j] * W[s][j * oc + c];
      on[c] = acc;
    }
    for (int c = 0; c < 12; c++) xv[c] = (c < oc) ? on[c] : 0.f;
  }
  for (int hh = 0; hh < 6; hh++) pos_out[hh * 961 + i] = xv[hh];
}

// ---------------------------------------------------------------------------
// Kernel B: QKV GEMM.  grid 512, 4 waves x 32 rows (BM=128, rt=2).
// W^T staged in LDS one mat at a time (76.8 KB, b128 both sides from wqT).
// Q pre-scaled by scale*log2e.  Q,K swapped-MFMA -> [b][h][n][d];
// V normal -> vT[b][h][d][n].
// ---------------------------------------------------------------------------
#define SMEM_G (192 * 200 * 2)

__global__ __launch_bounds__(256) void qkv_gemm_kernel(
    const float* __restrict__ x, const bf16* __restrict__ wqT,
    const float* __restrict__ b_qkv, bf16* __restrict__ qw,
    bf16* __restrict__ kw, bf16* __restrict__ vwT) {
  extern __shared__ char smem[];
  bf16* wt = (bf16*)smem;   // [192 c][200 k]
  const int tid = threadIdx.x;
  const int lane = tid & 63, w = tid >> 6;
  const int cI = lane & 15, gI = lane >> 4;
  const int row0 = blockIdx.x * 128 + w * 32;
  const int b = blockIdx.x >> 1;
  const float QSCALE = 0.17677669529663687f * LOG2E;

  // A-fragments: 32 rows of x (f32 -> bf16), held across all 3 mats
  bf16x8 afr[2][6];
#pragma unroll
  for (int rt = 0; rt < 2; rt++) {
#pragma unroll
    for (int kk = 0; kk < 6; kk++) {
      const float* p = x + (size_t)(row0 + rt * 16 + cI) * 192 + kk * 32 + gI * 8;
      float4 f0 = *(const float4*)p;
      float4 f1 = *(const float4*)(p + 4);
      bf16x8 a;
      a[0] = (bf16)f0.x; a[1] = (bf16)f0.y; a[2] = (bf16)f0.z; a[3] = (bf16)f0.w;
      a[4] = (bf16)f1.x; a[5] = (bf16)f1.y; a[6] = (bf16)f1.z; a[7] = (bf16)f1.w;
      afr[rt][kk] = a;
    }
  }

#pragma unroll
  for (int mat = 0; mat < 3; mat++) {
    __syncthreads();   // all waves done reading previous mat's wt
#pragma unroll
    for (int it = 0; it < 18; it++) {
      int idx = it * 256 + tid;          // 192 rows x 24 chunks
      int c = idx / 24, ch = idx % 24;
      bf16x8 v8 = *(const bf16x8*)(wqT + (size_t)(mat * 192 + c) * 192 + ch * 8);
      *(bf16x8*)(wt + c * 200 + ch * 8) = v8;
    }
    __syncthreads();
#pragma unroll
    for (int ct = 0; ct < 12; ct++) {
      bf16x8 wfr[6];
#pragma unroll
      for (int kk = 0; kk < 6; kk++)
        wfr[kk] = *(const bf16x8*)(wt + (ct * 16 + cI) * 200 + kk * 32 + gI * 8);
      if (mat < 2) {
        f32x4 bv4 = *(const f32x4*)(b_qkv + mat * 192 + ct * 16 + gI * 4);
        bf16* dst = (mat == 0) ? qw : kw;
#pragma unroll
        for (int rt = 0; rt < 2; rt++) {
          f32x4 acc = {0.f, 0.f, 0.f, 0.f};
#pragma unroll
          for (int kk = 0; kk < 6; kk++) acc = MFMA(wfr[kk], afr[rt][kk], acc);
          int n = (row0 + rt * 16 + cI) & 255;
          int c0 = ct * 16 + gI * 4;
          int h = c0 >> 5, d0 = c0 & 31;
          bf16x4 o4;
          if (mat == 0) {
#pragma unroll
            for (int r = 0; r < 4; r++) o4[r] = (bf16)((acc[r] + bv4[r]) * QSCALE);
          } else {
#pragma unroll
            for (int r = 0; r < 4; r++) o4[r] = (bf16)(acc[r] + bv4[r]);
          }
          *(bf16x4*)(dst + ((size_t)(b * 6 + h) * 256 + n) * 32 + d0) = o4;
        }
      } else {
        float bv = b_qkv[384 + ct * 16 + cI];
        int c = ct * 16 + cI, h = c >> 5, d = c & 31;
#pragma unroll
        for (int rt = 0; rt < 2; rt++) {
          f32x4 acc = {0.f, 0.f, 0.f, 0.f};
#pragma unroll
          for (int kk = 0; kk < 6; kk++) acc = MFMA(afr[rt][kk], wfr[kk], acc);
          int n0 = ((row0 + rt * 16) & 255) + gI * 4;
          bf16x4 o4;
#pragma unroll
          for (int r = 0; r < 4; r++) o4[r] = (bf16)(acc[r] + bv);
          *(bf16x4*)(vwT + ((size_t)(b * 6 + h) * 32 + d) * 256 + n0) = o4;
        }
      }
    }
  }
}

// ---------------------------------------------------------------------------
// Kernel C: flash attention.  grid 1536 (b,h), 4 waves x 64 Q rows (rt=4).
// Swapped QK^T; softmax per-rt (low live regs); P via per-wave LDS tile.
// LDS: posh[961]f32 @0 (pad 3904) | pw 4 x [64][72] bf16 @3904.  40768 B
//   -> 4 blocks/CU.
// ---------------------------------------------------------------------------
#define SM_PW   3904
#define SMEM_A  (3904 + 4 * 64 * 72 * 2)

__global__ __launch_bounds__(256, 2) void attn_kernel(
    const bf16* __restrict__ qw, const bf16* __restrict__ kw,
    const bf16* __restrict__ vwT, const float* __restrict__ mask,
    const float* __restrict__ posg, bf16* __restrict__ ctx) {
  extern __shared__ char smem[];
  float* posh = (float*)smem;

  const int tid = threadIdx.x;
  const int bid = blockIdx.x;
  const int s_ = bid & 63, j_ = bid >> 6;          // mask slice; XCD = s%8
  const int g_ = j_ & 3, h = j_ >> 2;
  const int b = g_ * 64 + s_;

  const bf16* qb = qw  + (size_t)(b * 6 + h) * 8192;
  const bf16* kb = kw  + (size_t)(b * 6 + h) * 8192;
  const bf16* vb = vwT + (size_t)(b * 6 + h) * 8192;

  for (int i2 = tid; i2 < 961; i2 += 256) posh[i2] = posg[h * 961 + i2];
  __syncthreads();

  const int lane = tid & 63, w = tid >> 6;
  const int cI = lane & 15, gI = lane >> 4;
  const int qrow0 = w * 64;
  bf16* pw = (bf16*)(smem + SM_PW + w * 9216);     // per-wave [64][72]

  bf16x8 qfr[4];
#pragma unroll
  for (int rt = 0; rt < 4; rt++)
    qfr[rt] = *(const bf16x8*)(qb + (qrow0 + rt * 16 + cI) * 32 + gI * 8);

  const float* maskb = mask + (size_t)s_ * (256 * 256);

  f32x4 o[4][2];
  float mr[4], lr[4];
#pragma unroll
  for (int rt = 0; rt < 4; rt++) {
    o[rt][0] = (f32x4){0.f, 0.f, 0.f, 0.f};
    o[rt][1] = (f32x4){0.f, 0.f, 0.f, 0.f};
    mr[rt] = -3.0e38f; lr[rt] = 0.f;
  }

  for (int kt = 0; kt < 4; kt++) {
    bf16x8 kfr[4];
#pragma unroll
    for (int ct = 0; ct < 4; ct++)
      kfr[ct] = *(const bf16x8*)(kb + (kt * 64 + ct * 16 + cI) * 32 + gI * 8);
#pragma unroll
    for (int rt = 0; rt < 4; rt++) {
      f32x4 sa[4];
#pragma unroll
      for (int ct = 0; ct < 4; ct++) {
        f32x4 z = {0.f, 0.f, 0.f, 0.f};
        sa[ct] = MFMA(kfr[ct], qfr[rt], z);        // swapped: m@row-slot, n@cI
      }
      int rnb = (qrow0 >> 4) + rt;
      const float* mrow = maskb + (size_t)(qrow0 + rt * 16 + cI) * 256 + kt * 64;
#pragma unroll
      for (int ct = 0; ct < 4; ct++) {
        int base = (rnb - (kt * 4 + ct) + 15) * 31 + cI + 15 - gI * 4;
        f32x4 mv = *(const f32x4*)(mrow + ct * 16 + gI * 4);
#pragma unroll
        for (int r = 0; r < 4; r++)
          sa[ct][r] = fmaf(posh[base - r] + mv[r], LOG2E, sa[ct][r]);
      }
      float t = sa[0][0];
#pragma unroll
      for (int ct = 0; ct < 4; ct++)
#pragma unroll
        for (int r = 0; r < 4; r++) t = fmaxf(t, sa[ct][r]);
      t = fmaxf(t, __shfl_xor(t, 16));
      t = fmaxf(t, __shfl_xor(t, 32));
      float mn = fmaxf(mr[rt], t);
      float fsc = exp2f(mr[rt] - mn);
      mr[rt] = mn;
      float sum = 0.f;
#pragma unroll
      for (int ct = 0; ct < 4; ct++)
#pragma unroll
        for (int r = 0; r < 4; r++) {
          float pp = exp2f(sa[ct][r] - mn);
          sa[ct][r] = pp;
          sum += pp;
        }
      sum += __shfl_xor(sum, 16);
      sum += __shfl_xor(sum, 32);
      lr[rt] = lr[rt] * fsc + sum;
      float fr0 = __shfl(fsc, gI * 4 + 0);
      float fr1 = __shfl(fsc, gI * 4 + 1);
      float fr2 = __shfl(fsc, gI * 4 + 2);
      float fr3 = __shfl(fsc, gI * 4 + 3);
      o[rt][0][0] *= fr0; o[rt][1][0] *= fr0;
      o[rt][0][1] *= fr1; o[rt][1][1] *= fr1;
      o[rt][0][2] *= fr2; o[rt][1][2] *= fr2;
      o[rt][0][3] *= fr3; o[rt][1][3] *= fr3;
#pragma unroll
      for (int ct = 0; ct < 4; ct++) {
        bf16x4 p4;
#pragma unroll
        for (int r = 0; r < 4; r++) p4[r] = (bf16)sa[ct][r];
        *(bf16x4*)(pw + (rt * 16 + cI) * 72 + ct * 16 + gI * 4) = p4;
      }
    }
    // this wave's P writes must land before re-reading as A-frags
    asm volatile("s_waitcnt lgkmcnt(0)" ::: "memory");
    __builtin_amdgcn_sched_barrier(0);
#pragma unroll
    for (int kc = 0; kc < 2; kc++) {
      bf16x8 vfr[2];
#pragma unroll
      for (int c2 = 0; c2 < 2; c2++)
        vfr[c2] = *(const bf16x8*)(vb + (c2 * 16 + cI) * 256 + kt * 64 + kc * 32 + gI * 8);
#pragma unroll
      for (int rt = 0; rt < 4; rt++) {
        bf16x8 pfr = *(const bf16x8*)(pw + (rt * 16 + cI) * 72 + kc * 32 + gI * 8);
#pragma unroll
        for (int c2 = 0; c2 < 2; c2++)
          o[rt][c2] = MFMA(pfr, vfr[c2], o[rt][c2]);
      }
    }
  }
  // ---- epilogue: lr lives at lane cI -> broadcast to row-slots, normalize ----
#pragma unroll
  for (int rt = 0; rt < 4; rt++) {
    float l0 = __shfl(lr[rt], gI * 4 + 0);
    float l1 = __shfl(lr[rt], gI * 4 + 1);
    float l2 = __shfl(lr[rt], gI * 4 + 2);
    float l3 = __shfl(lr[rt], gI * 4 + 3);
    f32x4 linv = {1.f / l0, 1.f / l1, 1.f / l2, 1.f / l3};
#pragma unroll
    for (int c2 = 0; c2 < 2; c2++) {
#pragma unroll
      for (int r = 0; r < 4; r++) {
        int n = qrow0 + rt * 16 + gI * 4 + r;
        ctx[((size_t)(b << 8) + n) * 192 + h * 32 + c2 * 16 + cI] =
            (bf16)(o[rt][c2][r] * linv[r]);
      }
    }
  }
}

// ---------------------------------------------------------------------------
// Kernel D: out = ctx @ w_proj + b_proj.  grid 512, rt=2, W^T staged in LDS
// (b128 from wpT), swapped orientation -> float4 stores.
// ---------------------------------------------------------------------------
#define SMEM_C (192 * 200 * 2)

__global__ __launch_bounds__(256) void proj_kernel(
    const bf16* __restrict__ ctx, const bf16* __restrict__ wpT,
    const float* __restrict__ b_proj, float* __restrict__ out) {
  extern __shared__ char smem[];
  bf16* wt = (bf16*)smem;   // [192 c][200 k]
  const int tid = threadIdx.x;
#pragma unroll
  for (int it = 0; it < 18; it++) {
    int idx = it * 256 + tid;
    int c = idx / 24, ch = idx % 24;
    bf16x8 v8 = *(const bf16x8*)(wpT + (size_t)c * 192 + ch * 8);
    *(bf16x8*)(wt + c * 200 + ch * 8) = v8;
  }
  __syncthreads();
  const int lane = tid & 63, w = tid >> 6;
  const int cI = lane & 15, gI = lane >> 4;
  const int row0 = blockIdx.x * 128 + w * 32;
  bf16x8 afr[2][6];
#pragma unroll
  for (int rt = 0; rt < 2; rt++) {
#pragma unroll
    for (int kk = 0; kk < 6; kk++)
      afr[rt][kk] = *(const bf16x8*)(ctx + (size_t)(row0 + rt * 16 + cI) * 192 +
                                     kk * 32 + gI * 8);
  }
#pragma unroll
  for (int ct = 0; ct < 12; ct++) {
    bf16x8 wfr[6];
#pragma unroll
    for (int kk = 0; kk < 6; kk++)
      wfr[kk] = *(const bf16x8*)(wt + (ct * 16 + cI) * 200 + kk * 32 + gI * 8);
    f32x4 bv4 = *(const f32x4*)(b_proj + ct * 16 + gI * 4);
#pragma unroll
    for (int rt = 0; rt < 2; rt++) {
      f32x4 acc = {0.f, 0.f, 0.f, 0.f};
#pragma unroll
      for (int kk = 0; kk < 6; kk++) acc = MFMA(wfr[kk], afr[rt][kk], acc);
      f32x4 res;
#pragma unroll
      for (int r = 0; r < 4; r++) res[r] = acc[r] + bv4[r];
      *(f32x4*)(out + (size_t)(row0 + rt * 16 + cI) * 192 + ct * 16 + gI * 4) = res;
    }
  }
}

// ---------------------------------------------------------------------------
extern "C" void kernel_launch(void* const* d_in, const int* in_sizes, int n_in,
                              void* d_out, int out_size, void* d_ws, size_t ws_size,
                              hipStream_t stream) {
  (void)in_sizes; (void)n_in; (void)out_size; (void)ws_size;
  const float* x      = (const float*)d_in[0];
  const float* mask   = (const float*)d_in[1];
  const float* w_qkv  = (const float*)d_in[2];
  const float* b_qkv  = (const float*)d_in[3];
  const float* w_proj = (const float*)d_in[4];
  const float* b_proj = (const float*)d_in[5];
  const float* pw0    = (const float*)d_in[6];
  const float* pb0    = (const float*)d_in[7];
  const float* g1     = (const float*)d_in[8];
  const float* be1    = (const float*)d_in[9];
  const float* w1     = (const float*)d_in[10];
  const float* b1     = (const float*)d_in[11];
  const float* g2     = (const float*)d_in[12];
  const float* be2    = (const float*)d_in[13];
  const float* w2     = (const float*)d_in[14];
  const float* b2     = (const float*)d_in[15];
  const float* g3     = (const float*)d_in[16];
  const float* be3    = (const float*)d_in[17];
  const float* w3     = (const float*)d_in[18];
  const float* b3     = (const float*)d_in[19];

  // ws layout (peak ~96.3 MB):
  //   posw @ 0         (24576)
  //   wqT  @ 24576     (221184)   bf16 [576][192]
  //   wpT  @ 245760    (73728)    bf16 [192][192]
  //   qw   @ 319488    (25165824) bf16 [b][h][n][32]   (pre-scaled by s*log2e)
  //   kw   @ 25485312  (25165824)
  //   vwT  @ 50651136  (25165824) bf16 [b][h][32][n]
  //   ctx  @ 75816960  (25165824)
  char* ws = (char*)d_ws;
  float* posw = (float*)ws;
  bf16*  wqT  = (bf16*)(ws + 24576);
  bf16*  wpT  = (bf16*)(ws + 245760);
  bf16*  qw   = (bf16*)(ws + 319488);
  bf16*  kw   = (bf16*)(ws + 25485312);
  bf16*  vwT  = (bf16*)(ws + 50651136);
  bf16*  ctx  = (bf16*)(ws + 75816960);
  float* outp = (float*)d_out;

  hipFuncSetAttribute((const void*)qkv_gemm_kernel,
                      hipFuncAttributeMaxDynamicSharedMemorySize, SMEM_G);
  hipFuncSetAttribute((const void*)proj_kernel,
                      hipFuncAttributeMaxDynamicSharedMemorySize, SMEM_C);

  precast_kernel<<<dim3(576), dim3(256), 0, stream>>>(w_qkv, w_proj, wqT, wpT);
  pos_mlp_kernel<<<dim3(4), dim3(256), 0, stream>>>(
      pw0, pb0, g1, be1, w1, b1, g2, be2, w2, b2, g3, be3, w3, b3, posw);
  qkv_gemm_kernel<<<dim3(512), dim3(256), SMEM_G, stream>>>(
      x, wqT, b_qkv, qw, kw, vwT);
  attn_kernel<<<dim3(1536), dim3(256), SMEM_A, stream>>>(
      qw, kw, vwT, mask, posw, ctx);
  proj_kernel<<<dim3(512), dim3(256), SMEM_C, stream>>>(
      ctx, wpT, b_proj, outp);
}

// Round 6
// 142.033 us; speedup vs baseline: 1.7781x; 1.0255x over previous
//
#include <hip/hip_runtime.h>
#include <hip/hip_bf16.h>
#include <math.h>

typedef __bf16 bf16;
typedef __bf16 bf16x8 __attribute__((ext_vector_type(8)));
typedef __bf16 bf16x4 __attribute__((ext_vector_type(4)));
typedef float  f32x4  __attribute__((ext_vector_type(4)));

#define MFMA(a, b, c) __builtin_amdgcn_mfma_f32_16x16x32_bf16((a), (b), (c), 0, 0, 0)
#define LOG2E 1.4426950408889634f

// ---------------------------------------------------------------------------
// Kernel 0: precast w_qkv^T -> wqT (bf16 [576][192]) and w_proj^T -> wpT
// (bf16 [192][192]).
// ---------------------------------------------------------------------------
__global__ void precast_kernel(const float* __restrict__ w_qkv,
                               const float* __restrict__ w_proj,
                               bf16* __restrict__ wqT, bf16* __restrict__ wpT) {
  int idx = blockIdx.x * 256 + threadIdx.x;
  if (idx < 576 * 192) {
    int c = idx / 192, k = idx % 192;
    wqT[idx] = (bf16)w_qkv[k * 576 + c];
  } else {
    int i2 = idx - 576 * 192;
    if (i2 < 192 * 192) {
      int c = i2 / 192, k = i2 % 192;
      wpT[i2] = (bf16)w_proj[k * 192 + c];
    }
  }
}

// ---------------------------------------------------------------------------
// Kernel A: relative-position-bias MLP (961 rows, 2->12->12->12->6).
// Output pos_out[h][i] (head-major).
// ---------------------------------------------------------------------------
__global__ void pos_mlp_kernel(
    const float* __restrict__ pw0, const float* __restrict__ pb0,
    const float* __restrict__ g1,  const float* __restrict__ be1,
    const float* __restrict__ w1,  const float* __restrict__ b1,
    const float* __restrict__ g2,  const float* __restrict__ be2,
    const float* __restrict__ w2,  const float* __restrict__ b2,
    const float* __restrict__ g3,  const float* __restrict__ be3,
    const float* __restrict__ w3,  const float* __restrict__ b3,
    float* __restrict__ pos_out) {
  int i = blockIdx.x * blockDim.x + threadIdx.x;
  if (i >= 961) return;
  float bh = (float)(i / 31) - 15.0f;
  float bw = (float)(i % 31) - 15.0f;
  float xv[12];
#pragma unroll
  for (int j = 0; j < 12; j++) xv[j] = bh * pw0[j] + bw * pw0[12 + j] + pb0[j];
  const float* G[3]  = {g1, g2, g3};
  const float* BE[3] = {be1, be2, be3};
  const float* W[3]  = {w1, w2, w3};
  const float* BB[3] = {b1, b2, b3};
#pragma unroll
  for (int s = 0; s < 3; s++) {
    float m = 0.f;
#pragma unroll
    for (int j = 0; j < 12; j++) m += xv[j];
    m *= (1.0f / 12.0f);
    float v = 0.f;
#pragma unroll
    for (int j = 0; j < 12; j++) { float d = xv[j] - m; v += d * d; }
    v *= (1.0f / 12.0f);
    float inv = 1.0f / sqrtf(v + 1e-5f);
    float y[12];
#pragma unroll
    for (int j = 0; j < 12; j++) {
      float t = (xv[j] - m) * inv * G[s][j] + BE[s][j];
      y[j] = t > 0.f ? t : 0.f;
    }
    int oc = (s == 2) ? 6 : 12;
    float on[12];
    for (int c = 0; c < oc; c++) {
      float acc = BB[s][c];
#pragma unroll
      for (int j = 0; j < 12; j++) acc += y[j] * W[s][j * oc + c];
      on[c] = acc;
    }
    for (int c = 0; c < 12; c++) xv[c] = (c < oc) ? on[c] : 0.f;
  }
  for (int hh = 0; hh < 6; hh++) pos_out[hh * 961 + i] = xv[hh];
}

// ---------------------------------------------------------------------------
// Kernel B: QKV GEMM.  grid 512, 4 waves x 32 rows (BM=128, rt=2).
// W^T staged in LDS one mat at a time.  Q pre-scaled by scale*log2e.
// Q,K swapped-MFMA -> [b][h][n][d]; V normal -> vT[b][h][d][n].
// ---------------------------------------------------------------------------
#define SMEM_G (192 * 200 * 2)

__global__ __launch_bounds__(256) void qkv_gemm_kernel(
    const float* __restrict__ x, const bf16* __restrict__ wqT,
    const float* __restrict__ b_qkv, bf16* __restrict__ qw,
    bf16* __restrict__ kw, bf16* __restrict__ vwT) {
  extern __shared__ char smem[];
  bf16* wt = (bf16*)smem;   // [192 c][200 k]
  const int tid = threadIdx.x;
  const int lane = tid & 63, w = tid >> 6;
  const int cI = lane & 15, gI = lane >> 4;
  const int row0 = blockIdx.x * 128 + w * 32;
  const int b = blockIdx.x >> 1;
  const float QSCALE = 0.17677669529663687f * LOG2E;

  bf16x8 afr[2][6];
#pragma unroll
  for (int rt = 0; rt < 2; rt++) {
#pragma unroll
    for (int kk = 0; kk < 6; kk++) {
      const float* p = x + (size_t)(row0 + rt * 16 + cI) * 192 + kk * 32 + gI * 8;
      float4 f0 = *(const float4*)p;
      float4 f1 = *(const float4*)(p + 4);
      bf16x8 a;
      a[0] = (bf16)f0.x; a[1] = (bf16)f0.y; a[2] = (bf16)f0.z; a[3] = (bf16)f0.w;
      a[4] = (bf16)f1.x; a[5] = (bf16)f1.y; a[6] = (bf16)f1.z; a[7] = (bf16)f1.w;
      afr[rt][kk] = a;
    }
  }

#pragma unroll
  for (int mat = 0; mat < 3; mat++) {
    __syncthreads();
#pragma unroll
    for (int it = 0; it < 18; it++) {
      int idx = it * 256 + tid;
      int c = idx / 24, ch = idx % 24;
      bf16x8 v8 = *(const bf16x8*)(wqT + (size_t)(mat * 192 + c) * 192 + ch * 8);
      *(bf16x8*)(wt + c * 200 + ch * 8) = v8;
    }
    __syncthreads();
#pragma unroll
    for (int ct = 0; ct < 12; ct++) {
      bf16x8 wfr[6];
#pragma unroll
      for (int kk = 0; kk < 6; kk++)
        wfr[kk] = *(const bf16x8*)(wt + (ct * 16 + cI) * 200 + kk * 32 + gI * 8);
      if (mat < 2) {
        f32x4 bv4 = *(const f32x4*)(b_qkv + mat * 192 + ct * 16 + gI * 4);
        bf16* dst = (mat == 0) ? qw : kw;
#pragma unroll
        for (int rt = 0; rt < 2; rt++) {
          f32x4 acc = {0.f, 0.f, 0.f, 0.f};
#pragma unroll
          for (int kk = 0; kk < 6; kk++) acc = MFMA(wfr[kk], afr[rt][kk], acc);
          int n = (row0 + rt * 16 + cI) & 255;
          int c0 = ct * 16 + gI * 4;
          int h = c0 >> 5, d0 = c0 & 31;
          bf16x4 o4;
          if (mat == 0) {
#pragma unroll
            for (int r = 0; r < 4; r++) o4[r] = (bf16)((acc[r] + bv4[r]) * QSCALE);
          } else {
#pragma unroll
            for (int r = 0; r < 4; r++) o4[r] = (bf16)(acc[r] + bv4[r]);
          }
          *(bf16x4*)(dst + ((size_t)(b * 6 + h) * 256 + n) * 32 + d0) = o4;
        }
      } else {
        float bv = b_qkv[384 + ct * 16 + cI];
        int c = ct * 16 + cI, h = c >> 5, d = c & 31;
#pragma unroll
        for (int rt = 0; rt < 2; rt++) {
          f32x4 acc = {0.f, 0.f, 0.f, 0.f};
#pragma unroll
          for (int kk = 0; kk < 6; kk++) acc = MFMA(afr[rt][kk], wfr[kk], acc);
          int n0 = ((row0 + rt * 16) & 255) + gI * 4;
          bf16x4 o4;
#pragma unroll
          for (int r = 0; r < 4; r++) o4[r] = (bf16)(acc[r] + bv);
          *(bf16x4*)(vwT + ((size_t)(b * 6 + h) * 32 + d) * 256 + n0) = o4;
        }
      }
    }
  }
}

// ---------------------------------------------------------------------------
// Kernel C: flash attention.  grid 1536 (b,h), 4 waves x 64 Q rows (rt=4).
// Swapped QK^T.  Pos bias via per-lane-permuted bf16 table (1 ds_read_b64
// per 16x16 tile).  l-sum via ones-MFMA (no shuffles).  Defer-max THR=8.
// LDS: pos4h [31][64][4] bf16 @0 (15872B) | pw 4 x [64][72] bf16 @15872.
// Total 52736 B -> 3 blocks/CU.
// ---------------------------------------------------------------------------
#define SM_PW   15872
#define SMEM_A  (15872 + 4 * 64 * 72 * 2)

__global__ __launch_bounds__(256, 3) void attn_kernel(
    const bf16* __restrict__ qw, const bf16* __restrict__ kw,
    const bf16* __restrict__ vwT, const float* __restrict__ mask,
    const float* __restrict__ posg, bf16* __restrict__ ctx) {
  extern __shared__ char smem[];
  bf16* pos4h = (bf16*)smem;

  const int tid = threadIdx.x;
  const int bid = blockIdx.x;
  const int s_ = bid & 63, j_ = bid >> 6;          // mask slice; XCD = s%8
  const int g_ = j_ & 3, h = j_ >> 2;
  const int b = g_ * 64 + s_;

  const bf16* qb = qw  + (size_t)(b * 6 + h) * 8192;
  const bf16* kb = kw  + (size_t)(b * 6 + h) * 8192;
  const bf16* vb = vwT + (size_t)(b * 6 + h) * 8192;

  // ---- stage per-lane-permuted pos table: pos4h[row][lane][r] ----
  {
    int lane_ = tid & 63, r_ = tid >> 6;           // r_ in 0..3
    int cI_ = lane_ & 15, gI_ = lane_ >> 4;
    int dcol = cI_ - 4 * gI_ - r_ + 15;            // 0..30, always in range
    const float* pr = posg + h * 961 + dcol;
    for (int row = 0; row < 31; row++)
      pos4h[(row * 64 + lane_) * 4 + r_] = (bf16)(pr[row * 31] * LOG2E);
  }
  __syncthreads();

  const int lane = tid & 63, w = tid >> 6;
  const int cI = lane & 15, gI = lane >> 4;
  const int qrow0 = w * 64;
  bf16* pw = (bf16*)(smem + SM_PW + w * 9216);     // per-wave [64][72]

  bf16x8 qfr[4];
#pragma unroll
  for (int rt = 0; rt < 4; rt++)
    qfr[rt] = *(const bf16x8*)(qb + (qrow0 + rt * 16 + cI) * 32 + gI * 8);

  const float* maskb = mask + (size_t)s_ * (256 * 256);

  bf16x8 ones8;
#pragma unroll
  for (int j = 0; j < 8; j++) ones8[j] = (bf16)1.0f;

  f32x4 o[4][2];
  f32x4 ol[4];
  float mr[4];
#pragma unroll
  for (int rt = 0; rt < 4; rt++) {
    o[rt][0] = (f32x4){0.f, 0.f, 0.f, 0.f};
    o[rt][1] = (f32x4){0.f, 0.f, 0.f, 0.f};
    ol[rt]   = (f32x4){0.f, 0.f, 0.f, 0.f};
    mr[rt] = -3.0e38f;
  }

  for (int kt = 0; kt < 4; kt++) {
    bf16x8 kfr[4];
#pragma unroll
    for (int ct = 0; ct < 4; ct++)
      kfr[ct] = *(const bf16x8*)(kb + (kt * 64 + ct * 16 + cI) * 32 + gI * 8);
#pragma unroll
    for (int rt = 0; rt < 4; rt++) {
      f32x4 sa[4];
#pragma unroll
      for (int ct = 0; ct < 4; ct++) {
        f32x4 z = {0.f, 0.f, 0.f, 0.f};
        sa[ct] = MFMA(kfr[ct], qfr[rt], z);        // swapped: m@row-slot, n@cI
      }
      const float* mrow = maskb + (size_t)(qrow0 + rt * 16 + cI) * 256 + kt * 64;
#pragma unroll
      for (int ct = 0; ct < 4; ct++) {
        int rowi = (w * 4 + rt) - (kt * 4 + ct) + 15;   // wave-uniform, 0..30
        bf16x4 pv4 = *(const bf16x4*)(pos4h + (rowi * 64 + lane) * 4);
        f32x4 mv = *(const f32x4*)(mrow + ct * 16 + gI * 4);
#pragma unroll
        for (int r = 0; r < 4; r++)
          sa[ct][r] = fmaf(mv[r], LOG2E, sa[ct][r] + (float)pv4[r]);
      }
      // row max (n = cI): in-lane 16 + 2 cross-group shuffles
      float t = sa[0][0];
#pragma unroll
      for (int ct = 0; ct < 4; ct++)
#pragma unroll
        for (int r = 0; r < 4; r++) t = fmaxf(t, sa[ct][r]);
      t = fmaxf(t, __shfl_xor(t, 16));
      t = fmaxf(t, __shfl_xor(t, 32));
      // defer-max: only rescale when some row grew by > 8 (in log2 units)
      if (!__all(t - mr[rt] <= 8.0f)) {
        float mn = fmaxf(mr[rt], t);
        float fsc = exp2f(mr[rt] - mn);
        mr[rt] = mn;
        float fr0 = __shfl(fsc, gI * 4 + 0);
        float fr1 = __shfl(fsc, gI * 4 + 1);
        float fr2 = __shfl(fsc, gI * 4 + 2);
        float fr3 = __shfl(fsc, gI * 4 + 3);
        o[rt][0][0] *= fr0; o[rt][1][0] *= fr0; ol[rt][0] *= fr0;
        o[rt][0][1] *= fr1; o[rt][1][1] *= fr1; ol[rt][1] *= fr1;
        o[rt][0][2] *= fr2; o[rt][1][2] *= fr2; ol[rt][2] *= fr2;
        o[rt][0][3] *= fr3; o[rt][1][3] *= fr3; ol[rt][3] *= fr3;
      }
#pragma unroll
      for (int ct = 0; ct < 4; ct++) {
        bf16x4 p4;
#pragma unroll
        for (int r = 0; r < 4; r++) p4[r] = (bf16)exp2f(sa[ct][r] - mr[rt]);
        *(bf16x4*)(pw + (rt * 16 + cI) * 72 + ct * 16 + gI * 4) = p4;
      }
    }
    // this wave's P writes must land before re-reading as A-frags
    asm volatile("s_waitcnt lgkmcnt(0)" ::: "memory");
    __builtin_amdgcn_sched_barrier(0);
#pragma unroll
    for (int kc = 0; kc < 2; kc++) {
      bf16x8 vfr[2];
#pragma unroll
      for (int c2 = 0; c2 < 2; c2++)
        vfr[c2] = *(const bf16x8*)(vb + (c2 * 16 + cI) * 256 + kt * 64 + kc * 32 + gI * 8);
#pragma unroll
      for (int rt = 0; rt < 4; rt++) {
        bf16x8 pfr = *(const bf16x8*)(pw + (rt * 16 + cI) * 72 + kc * 32 + gI * 8);
        o[rt][0] = MFMA(pfr, vfr[0], o[rt][0]);
        o[rt][1] = MFMA(pfr, vfr[1], o[rt][1]);
        ol[rt]   = MFMA(pfr, ones8, ol[rt]);       // row-sums, same layout as o
      }
    }
  }
  // ---- epilogue: l already in row-slot layout -> plain divide ----
#pragma unroll
  for (int rt = 0; rt < 4; rt++) {
    f32x4 linv;
#pragma unroll
    for (int r = 0; r < 4; r++) linv[r] = 1.0f / ol[rt][r];
#pragma unroll
    for (int c2 = 0; c2 < 2; c2++) {
#pragma unroll
      for (int r = 0; r < 4; r++) {
        int n = qrow0 + rt * 16 + gI * 4 + r;
        ctx[((size_t)(b << 8) + n) * 192 + h * 32 + c2 * 16 + cI] =
            (bf16)(o[rt][c2][r] * linv[r]);
      }
    }
  }
}

// ---------------------------------------------------------------------------
// Kernel D: out = ctx @ w_proj + b_proj.  grid 512, rt=2, W^T staged in LDS,
// swapped orientation -> float4 stores.
// ---------------------------------------------------------------------------
#define SMEM_C (192 * 200 * 2)

__global__ __launch_bounds__(256) void proj_kernel(
    const bf16* __restrict__ ctx, const bf16* __restrict__ wpT,
    const float* __restrict__ b_proj, float* __restrict__ out) {
  extern __shared__ char smem[];
  bf16* wt = (bf16*)smem;   // [192 c][200 k]
  const int tid = threadIdx.x;
#pragma unroll
  for (int it = 0; it < 18; it++) {
    int idx = it * 256 + tid;
    int c = idx / 24, ch = idx % 24;
    bf16x8 v8 = *(const bf16x8*)(wpT + (size_t)c * 192 + ch * 8);
    *(bf16x8*)(wt + c * 200 + ch * 8) = v8;
  }
  __syncthreads();
  const int lane = tid & 63, w = tid >> 6;
  const int cI = lane & 15, gI = lane >> 4;
  const int row0 = blockIdx.x * 128 + w * 32;
  bf16x8 afr[2][6];
#pragma unroll
  for (int rt = 0; rt < 2; rt++) {
#pragma unroll
    for (int kk = 0; kk < 6; kk++)
      afr[rt][kk] = *(const bf16x8*)(ctx + (size_t)(row0 + rt * 16 + cI) * 192 +
                                     kk * 32 + gI * 8);
  }
#pragma unroll
  for (int ct = 0; ct < 12; ct++) {
    bf16x8 wfr[6];
#pragma unroll
    for (int kk = 0; kk < 6; kk++)
      wfr[kk] = *(const bf16x8*)(wt + (ct * 16 + cI) * 200 + kk * 32 + gI * 8);
    f32x4 bv4 = *(const f32x4*)(b_proj + ct * 16 + gI * 4);
#pragma unroll
    for (int rt = 0; rt < 2; rt++) {
      f32x4 acc = {0.f, 0.f, 0.f, 0.f};
#pragma unroll
      for (int kk = 0; kk < 6; kk++) acc = MFMA(wfr[kk], afr[rt][kk], acc);
      f32x4 res;
#pragma unroll
      for (int r = 0; r < 4; r++) res[r] = acc[r] + bv4[r];
      *(f32x4*)(out + (size_t)(row0 + rt * 16 + cI) * 192 + ct * 16 + gI * 4) = res;
    }
  }
}

// ---------------------------------------------------------------------------
extern "C" void kernel_launch(void* const* d_in, const int* in_sizes, int n_in,
                              void* d_out, int out_size, void* d_ws, size_t ws_size,
                              hipStream_t stream) {
  (void)in_sizes; (void)n_in; (void)out_size; (void)ws_size;
  const float* x      = (const float*)d_in[0];
  const float* mask   = (const float*)d_in[1];
  const float* w_qkv  = (const float*)d_in[2];
  const float* b_qkv  = (const float*)d_in[3];
  const float* w_proj = (const float*)d_in[4];
  const float* b_proj = (const float*)d_in[5];
  const float* pw0    = (const float*)d_in[6];
  const float* pb0    = (const float*)d_in[7];
  const float* g1     = (const float*)d_in[8];
  const float* be1    = (const float*)d_in[9];
  const float* w1     = (const float*)d_in[10];
  const float* b1     = (const float*)d_in[11];
  const float* g2     = (const float*)d_in[12];
  const float* be2    = (const float*)d_in[13];
  const float* w2     = (const float*)d_in[14];
  const float* b2     = (const float*)d_in[15];
  const float* g3     = (const float*)d_in[16];
  const float* be3    = (const float*)d_in[17];
  const float* w3     = (const float*)d_in[18];
  const float* b3     = (const float*)d_in[19];

  // ws layout (peak ~96.3 MB):
  //   posw @ 0         (24576)
  //   wqT  @ 24576     (221184)   bf16 [576][192]
  //   wpT  @ 245760    (73728)    bf16 [192][192]
  //   qw   @ 319488    (25165824) bf16 [b][h][n][32]   (pre-scaled by s*log2e)
  //   kw   @ 25485312  (25165824)
  //   vwT  @ 50651136  (25165824) bf16 [b][h][32][n]
  //   ctx  @ 75816960  (25165824)
  char* ws = (char*)d_ws;
  float* posw = (float*)ws;
  bf16*  wqT  = (bf16*)(ws + 24576);
  bf16*  wpT  = (bf16*)(ws + 245760);
  bf16*  qw   = (bf16*)(ws + 319488);
  bf16*  kw   = (bf16*)(ws + 25485312);
  bf16*  vwT  = (bf16*)(ws + 50651136);
  bf16*  ctx  = (bf16*)(ws + 75816960);
  float* outp = (float*)d_out;

  hipFuncSetAttribute((const void*)qkv_gemm_kernel,
                      hipFuncAttributeMaxDynamicSharedMemorySize, SMEM_G);
  hipFuncSetAttribute((const void*)proj_kernel,
                      hipFuncAttributeMaxDynamicSharedMemorySize, SMEM_C);

  precast_kernel<<<dim3(576), dim3(256), 0, stream>>>(w_qkv, w_proj, wqT, wpT);
  pos_mlp_kernel<<<dim3(4), dim3(256), 0, stream>>>(
      pw0, pb0, g1, be1, w1, b1, g2, be2, w2, b2, g3, be3, w3, b3, posw);
  qkv_gemm_kernel<<<dim3(512), dim3(256), SMEM_G, stream>>>(
      x, wqT, b_qkv, qw, kw, vwT);
  attn_kernel<<<dim3(1536), dim3(256), SMEM_A, stream>>>(
      qw, kw, vwT, mask, posw, ctx);
  proj_kernel<<<dim3(512), dim3(256), SMEM_C, stream>>>(
      ctx, wpT, b_proj, outp);
}